// Round 5
// baseline (267.335 us; speedup 1.0000x reference)
//
#include <hip/hip_runtime.h>

// Performer feature map: out[row][m] = exp( sum_k x[row][k]/scale * W[m][k] ) / sqrt(M)
// rows = B*H*L = 262144, K = D = 128, N = M = 128. Memory-bound (32 FLOP/byte).
//
// R5: R4 + NONTEMPORAL LOADS restored (single-variable A/B vs R4's 113.6 us).
//   Cross-round evidence: R0 (nt loads) ~75 us; R1/R3/R4 (plain loads, any store
//   policy/granularity) 107-118 us at only 3.4-3.5 TB/s, occupancy 38%, VALU 7%
//   -> latency-bound, not traffic-bound. x is a 134 MB stream touched exactly
//   once: plain loads thrash L1 (32 KiB) and L2 allocation; nt bypasses.
//   Everything else identical to R4: swapped-operand MFMA (row-major acc),
//   XOR-swizzled Wb (32768 B) + per-wave 16x32 Ob quarter-tiles (8192 B)
//   = 40960 B exactly -> 4 blocks/CU, grid 1024 = 256 CU x 4 (no straggler tail),
//   full-line (8 rows x 128 B) nt stores.

typedef __attribute__((ext_vector_type(8))) short bf16x8;   // MFMA A/B frag (4 VGPRs)
typedef __attribute__((ext_vector_type(4))) float f32x4;    // MFMA C/D frag + 16B vec ld/st
typedef __attribute__((ext_vector_type(4))) short short4v;

__device__ __forceinline__ short f2bf(float f) {
    // round-to-nearest-even fp32 -> bf16 (finite gaussian inputs; no NaN path)
    union { float f; unsigned u; } v; v.f = f;
    return (short)((v.u + 0x7fffu + ((v.u >> 16) & 1u)) >> 16);
}

__global__ __launch_bounds__(256, 4)
void performer_kernel(const float* __restrict__ x,
                      const float* __restrict__ Wf,
                      float* __restrict__ out,
                      int n_chunks) {   // chunk = 64 rows (4 waves x 16 rows)
    // Wb: 128x128 shorts, XOR swizzle on short-col: scol = col ^ ((row&7)<<3).
    //   Granule 8 shorts = 16 B = b128 read width -> reads stay contiguous.
    //   MFMA frag reads: 8 lanes per 4-bank group = hw minimum (conflict-free).
    __shared__ short Wb[128 * 128];      // 32768 B
    // Ob: per-wave 16x32 f32 quarter tile, XOR swizzle: col4 ^= (row&7) (4-float granule).
    __shared__ float Ob[4 * 16 * 32];    // 8192 B

    const int tid = threadIdx.x;

    // ---- Stage W -> LDS as bf16, scale 1/128^0.25 folded in. Coalesced float4 reads. ----
    {
        const float inv_scale = 0.29730177875068026f;  // 128^-0.25
        #pragma unroll
        for (int i = 0; i < 16; ++i) {
            int idx = i * 256 + tid;          // float4 index, 4096 total (128x128 fp32)
            int row = idx >> 5;
            int cs  = (idx & 31) << 2;        // short-col of this 4-short piece
            f32x4 v = reinterpret_cast<const f32x4*>(Wf)[idx];
            short4v s;
            s.x = f2bf(v.x * inv_scale);
            s.y = f2bf(v.y * inv_scale);
            s.z = f2bf(v.z * inv_scale);
            s.w = f2bf(v.w * inv_scale);
            // XOR affects bits >=3 only; cs&7 in {0,4} preserved within the 16 B group
            *reinterpret_cast<short4v*>(&Wb[row * 128 + (cs ^ ((row & 7) << 3))]) = s;
        }
    }
    __syncthreads();

    const int wave = tid >> 6;
    const int lane = tid & 63;
    const int m    = lane & 15;      // X-frag row (x-row within 16-tile); W-frag feature row
    const int quad = lane >> 4;      // k-subblock select; D feature-quad
    const int r8   = lane >> 3;      // epilogue readback: row within 8-group
    const int c8   = lane & 7;       // epilogue readback: 16 B chunk within 128 B
    float* obuf = &Ob[wave * 16 * 32];
    const float inv_sqrt_m = 0.08838834764831845f;  // 1/sqrt(128)

    for (int chunk = blockIdx.x; chunk < n_chunks; chunk += gridDim.x) {
        const long row0 = (long)chunk * 64 + wave * 16;
        const float* xrow = x + (row0 + m) * 128 + quad * 8;

        // ---- X tile: 4 k-steps x 8 floats/lane, 32 B contiguous per lane.
        //      NONTEMPORAL: x is streamed exactly once — bypass L1/L2 allocation. ----
        f32x4 av[4][2];
        #pragma unroll
        for (int ks = 0; ks < 4; ++ks) {
            const f32x4* p = reinterpret_cast<const f32x4*>(xrow + ks * 32);
            av[ks][0] = __builtin_nontemporal_load(p);
            av[ks][1] = __builtin_nontemporal_load(p + 1);
        }
        bf16x8 af[4];
        #pragma unroll
        for (int ks = 0; ks < 4; ++ks) {
            af[ks][0] = f2bf(av[ks][0].x);
            af[ks][1] = f2bf(av[ks][0].y);
            af[ks][2] = f2bf(av[ks][0].z);
            af[ks][3] = f2bf(av[ks][0].w);
            af[ks][4] = f2bf(av[ks][1].x);
            af[ks][5] = f2bf(av[ks][1].y);
            af[ks][6] = f2bf(av[ks][1].z);
            af[ks][7] = f2bf(av[ks][1].w);
        }

        // ---- 8 feature-tiles of 16: MFMA with SWAPPED operands (A=W, B=X) ----
        // D[feature][xrow]: col = lane&15 = xrow m, row = quad*4+r = feature in tile.
        f32x4 acc[8];
        #pragma unroll
        for (int nt = 0; nt < 8; ++nt) {
            f32x4 a = {0.f, 0.f, 0.f, 0.f};
            #pragma unroll
            for (int ks = 0; ks < 4; ++ks) {
                bf16x8 wf = *reinterpret_cast<const bf16x8*>(
                    &Wb[(nt * 16 + m) * 128 + ((ks * 32 + quad * 8) ^ ((m & 7) << 3))]);
                a = __builtin_amdgcn_mfma_f32_16x16x32_bf16(wf, af[ks], a, 0, 0, 0);
            }
            acc[nt] = a;
        }

        // ---- Epilogue: 4 quarters of 32 features. Per quarter: exp -> LDS 16x32
        //      tile (XOR-swizzled) -> read back 16 B/lane -> nt store 8 rows x 128 B
        //      contiguous per instruction. ----
        float* obase = out + row0 * 128;
        #pragma unroll
        for (int G = 0; G < 4; ++G) {
            #pragma unroll
            for (int half = 0; half < 2; ++half) {      // nt = 2G + half
                const int nt = 2 * G + half;
                f32x4 v;
                #pragma unroll
                for (int r = 0; r < 4; ++r)
                    v[r] = __expf(acc[nt][r]) * inv_sqrt_m;
                // local feature lf = half*16 + quad*4 + r; store at lf ^ ((m&7)<<2)
                const int col = (half * 16 + quad * 4) ^ ((m & 7) << 2);
                *reinterpret_cast<f32x4*>(&obuf[m * 32 + col]) = v;
            }
            // same-wave LDS RAW: compiler inserts lgkmcnt waits
            #pragma unroll
            for (int H = 0; H < 2; ++H) {
                const int row = H * 8 + r8;              // row&7 == r8
                f32x4 v = *reinterpret_cast<const f32x4*>(
                    &obuf[row * 32 + ((c8 * 4) ^ (r8 << 2))]);
                __builtin_nontemporal_store(v, reinterpret_cast<f32x4*>(
                    &obase[row * 128 + G * 32 + c8 * 4]));
            }
        }
    }
}

extern "C" void kernel_launch(void* const* d_in, const int* in_sizes, int n_in,
                              void* d_out, int out_size, void* d_ws, size_t ws_size,
                              hipStream_t stream) {
    const float* x  = (const float*)d_in[0];   // (B,H,L,D) fp32
    const float* Wf = (const float*)d_in[1];   // (M,D) fp32
    float* out = (float*)d_out;                // (B,H,L,M) fp32

    const int rows = out_size / 128;           // 262144
    const int n_chunks = rows / 64;            // 4096

    performer_kernel<<<dim3(1024), dim3(256), 0, stream>>>(x, Wf, out, n_chunks);
}

// Round 7
// 227.365 us; speedup vs baseline: 1.1758x; 1.1758x over previous
//
#include <hip/hip_runtime.h>
#include <hip/hip_bf16.h>

// Performer feature map: out[row][m] = exp( sum_k x[row][k]/scale * W[m][k] ) / sqrt(M)
// rows = B*H*L = 262144, K = D = 128, N = M = 128. Memory-bound (32 FLOP/byte).
// bf16 MFMA compute; LDS-transposed epilogue for full-line coalesced dwordx4 stores.
//
// R7 (= R6 resubmit; container-side bench failure, no kernel change):
//   EXACT re-submission of the session-0 champion (dur_us 226.8, kernel inferred
//   63-80 us — it sat below the ~80 us harness fills in top-5, so its counters were
//   never captured). Five rounds of variants (swapped-operand MFMA, XOR swizzles,
//   4 blocks/CU, every load/store-policy combo) all measured 102-118 us kernel.
//   Re-anchoring the champion in-session; if it lands >=83 us it finally becomes
//   visible in top-5 and we get its FETCH/WRITE signature.

typedef __attribute__((ext_vector_type(8))) short bf16x8;   // MFMA A/B frag (4 VGPRs)
typedef __attribute__((ext_vector_type(4))) float f32x4;    // MFMA C/D frag + 16B vec ld/st
typedef __attribute__((ext_vector_type(4))) short short4v;

#define WPITCH 136   // shorts; 272 B rows: b128 B-frag reads 16B-aligned, 2-way bank (free)
#define OPITCH 68    // floats; 272 B rows: b128 readback 16B-aligned, exactly 8 acc/bank (min)

__device__ __forceinline__ short f2bf(float f) {
    // round-to-nearest-even fp32 -> bf16 (finite gaussian inputs; no NaN path)
    union { float f; unsigned u; } v; v.f = f;
    return (short)((v.u + 0x7fffu + ((v.u >> 16) & 1u)) >> 16);
}

__global__ __launch_bounds__(256)
void performer_kernel(const float* __restrict__ x,
                      const float* __restrict__ Wf,
                      float* __restrict__ out,
                      int n_chunks) {   // chunk = 64 rows (4 waves x 16 rows)
    __shared__ short Wb[128 * WPITCH];        // 34816 B
    __shared__ float Ob[4 * 16 * OPITCH];     // 17408 B (per-wave 16x64 transpose buffers)

    const int tid = threadIdx.x;

    // ---- Stage W -> LDS as bf16, scale 1/128^0.25 folded in. Coalesced float4 reads. ----
    {
        const float inv_scale = 0.29730177875068026f;  // 128^-0.25
        #pragma unroll
        for (int i = 0; i < 16; ++i) {
            int idx = i * 256 + tid;          // float4 index, 4096 total (128x128 fp32)
            int row = idx >> 5;
            int col = (idx & 31) << 2;
            f32x4 v = reinterpret_cast<const f32x4*>(Wf)[idx];
            short4v s;
            s.x = f2bf(v.x * inv_scale);
            s.y = f2bf(v.y * inv_scale);
            s.z = f2bf(v.z * inv_scale);
            s.w = f2bf(v.w * inv_scale);
            *reinterpret_cast<short4v*>(&Wb[row * WPITCH + col]) = s;
        }
    }
    __syncthreads();

    const int wave = tid >> 6;
    const int lane = tid & 63;
    const int m    = lane & 15;      // A-row within 16-tile; B-col within n-tile
    const int quad = lane >> 4;      // k-subblock select; C/D row group
    const int rrow = lane >> 3;      // epilogue readback: 8 lanes per row
    const int rcol = (lane & 7) * 4; // epilogue readback: float4 column
    float* obuf = &Ob[wave * 16 * OPITCH];
    const float inv_sqrt_m = 0.08838834764831845f;  // 1/sqrt(128)

    for (int chunk = blockIdx.x; chunk < n_chunks; chunk += gridDim.x) {
        const long row0 = (long)chunk * 64 + wave * 16;
        const float* xrow = x + (row0 + m) * 128 + quad * 8;

        // ---- A tile: 4 k-steps x 8 floats/lane (2x dwordx4, nontemporal: streamed) ----
        f32x4 av[4][2];
        #pragma unroll
        for (int ks = 0; ks < 4; ++ks) {
            const f32x4* p = reinterpret_cast<const f32x4*>(xrow + ks * 32);
            av[ks][0] = __builtin_nontemporal_load(p);
            av[ks][1] = __builtin_nontemporal_load(p + 1);
        }
        bf16x8 af[4];
        #pragma unroll
        for (int ks = 0; ks < 4; ++ks) {
            af[ks][0] = f2bf(av[ks][0].x);
            af[ks][1] = f2bf(av[ks][0].y);
            af[ks][2] = f2bf(av[ks][0].z);
            af[ks][3] = f2bf(av[ks][0].w);
            af[ks][4] = f2bf(av[ks][1].x);
            af[ks][5] = f2bf(av[ks][1].y);
            af[ks][6] = f2bf(av[ks][1].z);
            af[ks][7] = f2bf(av[ks][1].w);
        }

        // ---- 8 n-tiles of 16 cols: MFMA accumulate ----
        f32x4 acc[8];
        #pragma unroll
        for (int nt = 0; nt < 8; ++nt) {
            f32x4 a = {0.f, 0.f, 0.f, 0.f};
            #pragma unroll
            for (int ks = 0; ks < 4; ++ks) {
                bf16x8 bf = *reinterpret_cast<const bf16x8*>(
                    &Wb[(nt * 16 + m) * WPITCH + ks * 32 + quad * 8]);
                a = __builtin_amdgcn_mfma_f32_16x16x32_bf16(af[ks], bf, a, 0, 0, 0);
            }
            acc[nt] = a;
        }

        // ---- Epilogue: exp, transpose 16x64 half-tiles through LDS, dwordx4 stores ----
        float* orow = out + row0 * 128;
        #pragma unroll
        for (int h = 0; h < 2; ++h) {
            #pragma unroll
            for (int nt2 = 0; nt2 < 4; ++nt2) {
                #pragma unroll
                for (int r = 0; r < 4; ++r) {
                    // C/D layout: col = lane&15, row = quad*4 + r
                    obuf[(quad * 4 + r) * OPITCH + nt2 * 16 + m] =
                        __expf(acc[h * 4 + nt2][r]) * inv_sqrt_m;
                }
            }
            // same-wave LDS RAW/WAR: compiler inserts lgkmcnt waits
            #pragma unroll
            for (int rs = 0; rs < 2; ++rs) {
                #pragma unroll
                for (int j = 0; j < 2; ++j) {
                    f32x4 v = *reinterpret_cast<const f32x4*>(
                        &obuf[(rs * 8 + rrow) * OPITCH + j * 32 + rcol]);
                    // per store instr: 8 rows x 128 B contiguous aligned segments
                    __builtin_nontemporal_store(v, reinterpret_cast<f32x4*>(
                        &orow[(rs * 8 + rrow) * 128 + h * 64 + j * 32 + rcol]));
                }
            }
        }
    }
}

extern "C" void kernel_launch(void* const* d_in, const int* in_sizes, int n_in,
                              void* d_out, int out_size, void* d_ws, size_t ws_size,
                              hipStream_t stream) {
    const float* x  = (const float*)d_in[0];   // (B,H,L,D) fp32
    const float* Wf = (const float*)d_in[1];   // (M,D) fp32
    float* out = (float*)d_out;                // (B,H,L,M) fp32

    const int rows = out_size / 128;           // 262144
    const int n_chunks = rows / 64;            // 4096

    performer_kernel<<<dim3(1024), dim3(256), 0, stream>>>(x, Wf, out, n_chunks);
}